// Round 1
// baseline (528.797 us; speedup 1.0000x reference)
//
#include <hip/hip_runtime.h>

#define H   512
#define W   512
#define HP  256   // row pairs (output height per quadrant)
#define WP  256   // output columns per quadrant
#define JSEG 64   // row-pairs per segment
#define SEGS (HP / JSEG)   // 4
#define IMGS 256  // 8*32

// d_row[k] = p[2k+1] - 0.5*(p[2*em(k-1)] + p[2*em(k+1)]), em(-1)=1, em(256)=254
__device__ __forceinline__ float dr_scalar(const float* __restrict__ p, int k) {
    int a  = (k == 0)   ? 2   : (2 * k - 2);
    int b2 = (k == 255) ? 508 : (2 * k + 2);
    return p[2 * k + 1] - 0.5f * (p[a] + p[b2]);
}

// Row transform at column c of a 512-float row: s (lowpass), d (highpass)
__device__ __forceinline__ void row_lift(const float* __restrict__ p, int c, bool mainPath,
                                         float& s, float& d) {
    if (mainPath) {  // c in [2,253]: all loads in-bounds, no index mapping triggers
        float2 vm2 = *(const float2*)(p + 2 * c - 4);
        float2 vm1 = *(const float2*)(p + 2 * c - 2);
        float2 v0  = *(const float2*)(p + 2 * c);
        float2 vp1 = *(const float2*)(p + 2 * c + 2);
        float2 vp2 = *(const float2*)(p + 2 * c + 4);
        float dm = vm1.y - 0.5f * (vm2.x + v0.x);   // d[c-1]
        float d0 = v0.y  - 0.5f * (vm1.x + vp1.x);  // d[c]
        float dp = vp1.y - 0.5f * (v0.x  + vp2.x);  // d[c+1]
        s = v0.x + 0.25f * (dm + dp);
        d = d0;
    } else {         // c in {0,1,254,255}: reflect-mapped indices
        int cm = (c == 0)   ? 1   : c - 1;   // d[-1] -> d[1]
        int cp = (c == 255) ? 254 : c + 1;   // d[256] -> d[254]
        float dm = dr_scalar(p, cm);
        float d0 = dr_scalar(p, c);
        float dp = dr_scalar(p, cp);
        s = p[2 * c] + 0.25f * (dm + dp);
        d = d0;
    }
}

__global__ __launch_bounds__(256, 4)
void lwt53_2d_fused(const float* __restrict__ x, float* __restrict__ out) {
    const int c   = threadIdx.x;            // output column 0..255
    const int img = blockIdx.x / SEGS;      // 0..255  (= b*32 + ch)
    const int seg = blockIdx.x % SEGS;
    const int j0  = seg * JSEG;

    const float* ib = x + (size_t)img * (H * W);
    const int b  = img >> 5;
    const int ch = img & 31;
    // out[((b*128 + q*32 + ch)*256 + row)*256 + col], q: 0=LL 1=LH 2=HL 3=HH
    float* const outLL = out + (((size_t)b * 128 +  0 + ch) << 16) + c;
    float* const outLH = out + (((size_t)b * 128 + 32 + ch) << 16) + c;
    float* const outHL = out + (((size_t)b * 128 + 64 + ch) << 16) + c;
    float* const outHH = out + (((size_t)b * 128 + 96 + ch) << 16) + c;

    // Column-lifting pipeline state (per branch): e[j-1], e[j-2], o[j-1],
    // dcol[j-2], dcol[j-3]
    float e1s = 0.f, e2s = 0.f, o1s = 0.f, dc1s = 0.f, dc2s = 0.f;
    float e1d = 0.f, e2d = 0.f, o1d = 0.f, dc1d = 0.f, dc2d = 0.f;

    const int js = (seg == 0) ? 0 : (j0 - 2);
    const int je = j0 + JSEG + 1;           // inclusive; 257 for last segment

    const bool mainPath = (c >= 2) && (c <= 253);
    const bool firstSeg = (seg == 0);

    for (int j = js; j <= je; ++j) {
        float es, ed, os, od;
        if (j <= HP - 1) {
            const float* p0 = ib + (size_t)(2 * j) * W;
            row_lift(p0,     c, mainPath, es, ed);   // even row 2j
            row_lift(p0 + W, c, mainPath, os, od);   // odd row 2j+1
        } else {
            es = e2s; ed = e2d;                      // e[256] -> e[254]
            os = 0.f; od = 0.f;
        }

        // dcol[j-1] = o[j-1] - 0.5*(e[j-2] + e[j])   (e[-1]->e[1] at j==1,seg0)
        float dnew_s, dnew_d;
        if (j == 257) {                              // dcol[256] -> dcol[254]
            dnew_s = dc2s; dnew_d = dc2d;
        } else {
            float e2s_eff = (firstSeg && j == 1) ? es : e2s;
            float e2d_eff = (firstSeg && j == 1) ? ed : e2d;
            dnew_s = o1s - 0.5f * (e2s_eff + es);
            dnew_d = o1d - 0.5f * (e2d_eff + ed);
        }

        const int rD = j - 1;
        if (rD >= j0 && rD < j0 + JSEG) {
            outLH[rD * WP] = dnew_s;
            outHH[rD * WP] = dnew_d;
        }

        // scol[j-2] = e[j-2] + 0.25*(dcol[j-3] + dcol[j-1])  (dcol[-1]->dcol[1])
        float dc2s_eff = (firstSeg && j == 2) ? dnew_s : dc2s;
        float dc2d_eff = (firstSeg && j == 2) ? dnew_d : dc2d;
        float snew_s = e2s + 0.25f * (dc2s_eff + dnew_s);
        float snew_d = e2d + 0.25f * (dc2d_eff + dnew_d);

        const int rS = j - 2;
        if (rS >= j0 && rS < j0 + JSEG) {
            outLL[rS * WP] = snew_s;
            outHL[rS * WP] = snew_d;
        }

        // shift pipeline
        dc2s = dc1s; dc1s = dnew_s; e2s = e1s; e1s = es; o1s = os;
        dc2d = dc1d; dc1d = dnew_d; e2d = e1d; e1d = ed; o1d = od;
    }
}

extern "C" void kernel_launch(void* const* d_in, const int* in_sizes, int n_in,
                              void* d_out, int out_size, void* d_ws, size_t ws_size,
                              hipStream_t stream) {
    const float* x = (const float*)d_in[0];
    float* out = (float*)d_out;
    dim3 grid(IMGS * SEGS);   // 1024 blocks
    dim3 block(256);
    hipLaunchKernelGGL(lwt53_2d_fused, grid, block, 0, stream, x, out);
}

// Round 2
// 513.209 us; speedup vs baseline: 1.0304x; 1.0304x over previous
//
#include <hip/hip_runtime.h>

#define H   512
#define W   512
#define HP  256   // row pairs (output height per quadrant)
#define WP  256   // output columns per quadrant
#define JSEG 32   // row-pairs per segment (32 -> 2048 blocks -> 32 waves/CU)
#define SEGS (HP / JSEG)   // 8
#define IMGS 256  // 8*32

// d_row[k] = p[2k+1] - 0.5*(p[2*em(k-1)] + p[2*em(k+1)]), em(-1)=1, em(256)=254
__device__ __forceinline__ float dr_scalar(const float* __restrict__ p, int k) {
    int a  = (k == 0)   ? 2   : (2 * k - 2);
    int b2 = (k == 255) ? 508 : (2 * k + 2);
    return p[2 * k + 1] - 0.5f * (p[a] + p[b2]);
}

// Row transform at column c of a 512-float row: s (lowpass), d (highpass)
__device__ __forceinline__ void row_lift(const float* __restrict__ p, int c, bool mainPath,
                                         float& s, float& d) {
    if (mainPath) {  // c in [2,253]: all loads in-bounds, no index mapping triggers
        float2 vm2 = *(const float2*)(p + 2 * c - 4);
        float2 vm1 = *(const float2*)(p + 2 * c - 2);
        float2 v0  = *(const float2*)(p + 2 * c);
        float2 vp1 = *(const float2*)(p + 2 * c + 2);
        float2 vp2 = *(const float2*)(p + 2 * c + 4);
        float dm = vm1.y - 0.5f * (vm2.x + v0.x);   // d[c-1]
        float d0 = v0.y  - 0.5f * (vm1.x + vp1.x);  // d[c]
        float dp = vp1.y - 0.5f * (v0.x  + vp2.x);  // d[c+1]
        s = v0.x + 0.25f * (dm + dp);
        d = d0;
    } else {         // c in {0,1,254,255}: reflect-mapped indices
        int cm = (c == 0)   ? 1   : c - 1;   // d[-1] -> d[1]
        int cp = (c == 255) ? 254 : c + 1;   // d[256] -> d[254]
        float dm = dr_scalar(p, cm);
        float d0 = dr_scalar(p, c);
        float dp = dr_scalar(p, cp);
        s = p[2 * c] + 0.25f * (dm + dp);
        d = d0;
    }
}

__global__ __launch_bounds__(256, 8)
void lwt53_2d_fused(const float* __restrict__ x, float* __restrict__ out) {
    const int c   = threadIdx.x;            // output column 0..255
    const int img = blockIdx.x / SEGS;      // 0..255  (= b*32 + ch)
    const int seg = blockIdx.x % SEGS;
    const int j0  = seg * JSEG;

    const float* ib = x + (size_t)img * (H * W);
    const int b  = img >> 5;
    const int ch = img & 31;
    // out[((b*128 + q*32 + ch)*256 + row)*256 + col], q: 0=LL 1=LH 2=HL 3=HH
    float* const outLL = out + (((size_t)b * 128 +  0 + ch) << 16) + c;
    float* const outLH = out + (((size_t)b * 128 + 32 + ch) << 16) + c;
    float* const outHL = out + (((size_t)b * 128 + 64 + ch) << 16) + c;
    float* const outHH = out + (((size_t)b * 128 + 96 + ch) << 16) + c;

    // Column-lifting pipeline state (per branch): e[j-1], e[j-2], o[j-1],
    // dcol[j-2], dcol[j-3]
    float e1s = 0.f, e2s = 0.f, o1s = 0.f, dc1s = 0.f, dc2s = 0.f;
    float e1d = 0.f, e2d = 0.f, o1d = 0.f, dc1d = 0.f, dc2d = 0.f;

    const int js = (seg == 0) ? 0 : (j0 - 2);
    const int je = j0 + JSEG + 1;           // inclusive; 257 for last segment

    const bool mainPath = (c >= 2) && (c <= 253);
    const bool firstSeg = (seg == 0);

    for (int j = js; j <= je; ++j) {
        float es, ed, os, od;
        if (j <= HP - 1) {
            const float* p0 = ib + (size_t)(2 * j) * W;
            row_lift(p0,     c, mainPath, es, ed);   // even row 2j
            row_lift(p0 + W, c, mainPath, os, od);   // odd row 2j+1
        } else {
            es = e2s; ed = e2d;                      // e[256] -> e[254]
            os = 0.f; od = 0.f;
        }

        // dcol[j-1] = o[j-1] - 0.5*(e[j-2] + e[j])   (e[-1]->e[1] at j==1,seg0)
        float dnew_s, dnew_d;
        if (j == 257) {                              // dcol[256] -> dcol[254]
            dnew_s = dc2s; dnew_d = dc2d;
        } else {
            float e2s_eff = (firstSeg && j == 1) ? es : e2s;
            float e2d_eff = (firstSeg && j == 1) ? ed : e2d;
            dnew_s = o1s - 0.5f * (e2s_eff + es);
            dnew_d = o1d - 0.5f * (e2d_eff + ed);
        }

        const int rD = j - 1;
        if (rD >= j0 && rD < j0 + JSEG) {
            outLH[rD * WP] = dnew_s;
            outHH[rD * WP] = dnew_d;
        }

        // scol[j-2] = e[j-2] + 0.25*(dcol[j-3] + dcol[j-1])  (dcol[-1]->dcol[1])
        float dc2s_eff = (firstSeg && j == 2) ? dnew_s : dc2s;
        float dc2d_eff = (firstSeg && j == 2) ? dnew_d : dc2d;
        float snew_s = e2s + 0.25f * (dc2s_eff + dnew_s);
        float snew_d = e2d + 0.25f * (dc2d_eff + dnew_d);

        const int rS = j - 2;
        if (rS >= j0 && rS < j0 + JSEG) {
            outLL[rS * WP] = snew_s;
            outHL[rS * WP] = snew_d;
        }

        // shift pipeline
        dc2s = dc1s; dc1s = dnew_s; e2s = e1s; e1s = es; o1s = os;
        dc2d = dc1d; dc1d = dnew_d; e2d = e1d; e1d = ed; o1d = od;
    }
}

extern "C" void kernel_launch(void* const* d_in, const int* in_sizes, int n_in,
                              void* d_out, int out_size, void* d_ws, size_t ws_size,
                              hipStream_t stream) {
    const float* x = (const float*)d_in[0];
    float* out = (float*)d_out;
    dim3 grid(IMGS * SEGS);   // 2048 blocks
    dim3 block(256);
    hipLaunchKernelGGL(lwt53_2d_fused, grid, block, 0, stream, x, out);
}